// Round 14
// baseline (170.034 us; speedup 1.0000x reference)
//
#include <hip/hip_runtime.h>
#include <math.h>

#define KK 1024
#define DD 64
#define BS 65536              // 2048*32 rows
#define TM 32                 // rows per block
#define NBLK (BS/TM)          // 2048
#define NTHR 512
#define LN_2PI 1.8378770664093453f
#define DECAY 0.9f

typedef _Float16 f16x8 __attribute__((ext_vector_type(8)));
typedef float f32x16 __attribute__((ext_vector_type(16)));

// ws layout in FLOAT units:
//  [BH_OFF, +65536)  W_hi fp16 [16 kblk][1024 col][8 k]
//  [BL_OFF, +65536)  W_lo fp16 same layout
//  [C_OFF,  +1024)   c[k]
//  [SIG_OFF,+65536)  sigma[k][d] fp32
//  [RESP_OFF,+1024)  resp accumulator
#define BH_OFF   0
#define BL_OFF   65536
#define C_OFF    131072
#define SIG_OFF  (C_OFF + KK)
#define RESP_OFF (SIG_OFF + KK*DD)

// dynamic LDS: Bb[2][64KB] + mxl[32*8] + sml[32*8] + gm[32] + inv[32] + am[32]
#define SMEM_BYTES (131072 + 1024 + 1024 + 128 + 128 + 128)

__global__ __launch_bounds__(64) void prep_kernel(
    const float* __restrict__ mu, const float* __restrict__ log_sigma,
    float* __restrict__ ws) {
  int k = blockIdx.x;
  int d = threadIdx.x;
  float ls = log_sigma[k*DD + d];
  float m  = mu[k*DD + d];
  float iv = expf(-2.0f*ls);
  _Float16* Bh = (_Float16*)(ws + BH_OFF);
  _Float16* Bl = (_Float16*)(ws + BL_OFF);
  {
    float w0 = -0.5f*iv;                    // coeff of s^2 (dd = d)
    _Float16 hh = (_Float16)w0;
    Bh[((size_t)(d >> 3)*KK + k)*8 + (d & 7)] = hh;
    Bl[((size_t)(d >> 3)*KK + k)*8 + (d & 7)] = (_Float16)(w0 - (float)hh);
  }
  {
    float w1 = m*iv;                        // coeff of s (dd = 64+d)
    _Float16 hh = (_Float16)w1;
    int dd = 64 + d;
    Bh[((size_t)(dd >> 3)*KK + k)*8 + (dd & 7)] = hh;
    Bl[((size_t)(dd >> 3)*KK + k)*8 + (dd & 7)] = (_Float16)(w1 - (float)hh);
  }
  ws[SIG_OFF + k*DD + d] = expf(ls);
  float t1 = m*m*iv;
  float t2 = ls;
  #pragma unroll
  for (int off = 32; off; off >>= 1) {
    t1 += __shfl_xor(t1, off);
    t2 += __shfl_xor(t2, off);
  }
  if (d == 0) ws[C_OFF + k] = -0.5f*t1 - t2 - 32.0f*LN_2PI;
}

// async global->LDS, 16B per lane; LDS dst = wave-uniform base + lane*16
#define GLD16(g, l) __builtin_amdgcn_global_load_lds( \
    (const __attribute__((address_space(1))) void*)(g), \
    (__attribute__((address_space(3))) void*)(l), 16, 0, 0)

// stage k-slice s (64KB: hi 32KB + lo 32KB) into buf[s&1]; 8 loads/thread
#define STAGE(s) do { \
  const char* _sh = wsB0 + (size_t)(s)*32768; \
  const char* _sl = wsB1 + (size_t)(s)*32768; \
  char* _d = Bbase + (((s)&1) ? 65536 : 0); \
  _Pragma("unroll") \
  for (int _r = 0; _r < 4; ++_r) { \
    const int _o = (_r*512 + t)*16; \
    GLD16(_sh + _o, _d + _o); \
    GLD16(_sl + _o, _d + 32768 + _o); \
  } \
} while (0)

// one K=16 slice:
//   vmcnt(N)[mem] ; bar ; fence ; ds_read+MFMA ; fence ; bar ; STAGE(s+2)
// Half-index arithmetic (R13 bugfix): lo region starts at HALF offset 16384
// (byte 32768); the f16x8 index must be scaled by 8 BEFORE adding it:
//   half_idx = 16384 + 8*((h<<10) + col0 + ct*32)      [was (16384+idx)*8 —
//   byte 262144+, outside the 64KB buffer -> bl read garbage -> absmax 47]
#define ITER(s, VN) do { \
  asm volatile("s_waitcnt vmcnt(" #VN ")" ::: "memory"); \
  __builtin_amdgcn_s_barrier(); \
  asm volatile("" ::: "memory"); \
  const _Float16* _bp = (const _Float16*)(Bbase + (((s)&1) ? 65536 : 0)); \
  _Pragma("unroll") \
  for (int ct = 0; ct < 4; ++ct) { \
    f16x8 bh = *(const f16x8*)&_bp[(size_t)((h << 10) + col0 + ct*32) * 8]; \
    f16x8 bl = *(const f16x8*)&_bp[16384 + (size_t)((h << 10) + col0 + ct*32) * 8]; \
    acc[ct] = __builtin_amdgcn_mfma_f32_32x32x16_f16(Ahreg[(s)], bh, acc[ct], 0, 0, 0); \
    acc[ct] = __builtin_amdgcn_mfma_f32_32x32x16_f16(Ahreg[(s)], bl, acc[ct], 0, 0, 0); \
    acc[ct] = __builtin_amdgcn_mfma_f32_32x32x16_f16(Alreg[(s)], bh, acc[ct], 0, 0, 0); \
  } \
  asm volatile("" ::: "memory"); \
  __builtin_amdgcn_s_barrier(); \
  asm volatile("" ::: "memory"); \
  if ((s) + 2 < 8) STAGE((s) + 2); \
} while (0)

__global__ __launch_bounds__(512, 2) void main_kernel(
    const float* __restrict__ slots, const float* __restrict__ mu,
    const float* __restrict__ z, const float* __restrict__ ws,
    float* __restrict__ out_slots, float* __restrict__ out_ll,
    float* __restrict__ resp_g) {
  extern __shared__ char smem[];
  char*  Bbase = smem;                         // 2 x 64KB B slice buffers
  float* mxl   = (float*)(smem + 131072);      // [32][8]
  float* sml   = mxl + 256;                    // [32][8]
  float* gm_l  = sml + 256;                    // [32]
  float* inv_l = gm_l + 32;                    // [32]
  int*   am_l  = (int*)(inv_l + 32);           // [32]

  const int t    = threadIdx.x;
  const int lane = t & 63;
  const int w    = t >> 6;           // wave = 128-col group
  const int h    = lane >> 5;        // k half (0/1)
  const int lc   = lane & 31;        // col-in-tile (B/C/D) = slot row (A)
  const int R0   = blockIdx.x * TM;
  const int col0 = (w << 7) + lc;

  const char* wsB0 = (const char*)ws;                 // BH bytes
  const char* wsB1 = (const char*)ws + 262144;        // BL bytes

  // ---- A loads: lane (lc,h) needs slots[R0+lc][d], d = 16a+8h+b ----
  const float* arow = slots + (size_t)(R0 + lc)*DD + h*8;
  float4 a0[4], a1[4];
  #pragma unroll
  for (int a = 0; a < 4; ++a) {
    a0[a] = *(const float4*)(arow + a*16);
    a1[a] = *(const float4*)(arow + a*16 + 4);
  }
  // ---- acc init from c[k] ----
  f32x16 acc[4];
  {
    const float* Cc = ws + C_OFF;
    #pragma unroll
    for (int ct = 0; ct < 4; ++ct) {
      float cv = Cc[col0 + ct*32];
      f32x16 ini;
      #pragma unroll
      for (int j = 0; j < 16; ++j) ini[j] = cv;
      acc[ct] = ini;
    }
  }
  // ---- prologue: stage slices 0,1 (async, stays in flight) ----
  STAGE(0);
  STAGE(1);

  // ---- build A fragments in registers (overlaps staging latency) ----
  float av[32];
  #pragma unroll
  for (int a = 0; a < 4; ++a) {
    av[8*a+0] = a0[a].x; av[8*a+1] = a0[a].y; av[8*a+2] = a0[a].z; av[8*a+3] = a0[a].w;
    av[8*a+4] = a1[a].x; av[8*a+5] = a1[a].y; av[8*a+6] = a1[a].z; av[8*a+7] = a1[a].w;
  }
  f16x8 Ahreg[8], Alreg[8];
  #pragma unroll
  for (int s = 0; s < 4; ++s) {
    #pragma unroll
    for (int j = 0; j < 8; ++j) {
      float x = av[8*s + j];
      float sq = x * x;
      _Float16 h1 = (_Float16)sq;
      Ahreg[s][j] = h1;  Alreg[s][j] = (_Float16)(sq - (float)h1);
      _Float16 h2 = (_Float16)x;
      Ahreg[s+4][j] = h2; Alreg[s+4][j] = (_Float16)(x - (float)h2);
    }
  }
  if (t < TM) am_l[t] = 0x7fffffff;
  asm volatile("s_waitcnt lgkmcnt(0)" ::: "memory");

  // ---- K loop: 8 slices, 2-deep counted-vmcnt pipeline ----
  ITER(0, 8); ITER(1, 8); ITER(2, 8); ITER(3, 8);
  ITER(4, 8); ITER(5, 8); ITER(6, 8); ITER(7, 0);

  // C/D layout: col = col0 + ct*32, row = (q&3) + 8*(q>>2) + 4*h
  // ---- phase A: per-wave MAX ONLY ----
  #pragma unroll
  for (int q = 0; q < 16; ++q) {
    float m = fmaxf(fmaxf(acc[0][q], acc[1][q]), fmaxf(acc[2][q], acc[3][q]));
    #pragma unroll
    for (int off = 1; off < 32; off <<= 1)
      m = fmaxf(m, __shfl_xor(m, off));
    if (lc == 0) mxl[((q&3) + 8*(q>>2) + 4*h)*8 + w] = m;
  }
  __syncthreads();

  // ---- phase B: combine 8 waves -> global max, ll ----
  if (t < TM) {
    float m = mxl[t*8];
    #pragma unroll
    for (int g = 1; g < 8; ++g) m = fmaxf(m, mxl[t*8 + g]);
    gm_l[t] = m;
    out_ll[R0 + t] = m;
  }
  __syncthreads();

  // ---- phase C: argmax eq-scan + sparse atomicMin; exp in place; sums ----
  #pragma unroll
  for (int q = 0; q < 16; ++q) {
    const int row = (q&3) + 8*(q>>2) + 4*h;
    const float gm = gm_l[row];
    int cand = 0x7fffffff;
    #pragma unroll
    for (int ct = 3; ct >= 0; --ct)
      if (acc[ct][q] == gm) cand = col0 + ct*32;
    if (cand != 0x7fffffff) atomicMin(&am_l[row], cand);
    float sacc = 0.0f;
    #pragma unroll
    for (int ct = 0; ct < 4; ++ct) {
      float e = __expf(acc[ct][q] - gm);
      acc[ct][q] = e;
      sacc += e;
    }
    #pragma unroll
    for (int off = 1; off < 32; off <<= 1) sacc += __shfl_xor(sacc, off);
    if (lc == 0) sml[row*8 + w] = sacc;
  }
  __syncthreads();
  if (t < TM) {
    float ssum = 0.0f;
    #pragma unroll
    for (int g = 0; g < 8; ++g) ssum += sml[t*8 + g];
    inv_l[t] = 1.0f / ssum;
  }
  __syncthreads();

  // ---- phase E: responsibilities -> direct atomics (wave-owned cols) ----
  {
    float rc[4] = {0.0f, 0.0f, 0.0f, 0.0f};
    #pragma unroll
    for (int q = 0; q < 16; ++q) {
      int row = (q&3) + 8*(q>>2) + 4*h;
      float inv = inv_l[row];
      #pragma unroll
      for (int ct = 0; ct < 4; ++ct) rc[ct] += acc[ct][q] * inv;
    }
    #pragma unroll
    for (int ct = 0; ct < 4; ++ct) rc[ct] += __shfl_xor(rc[ct], 32);
    if (lane < 32) {
      #pragma unroll
      for (int ct = 0; ct < 4; ++ct) atomicAdd(resp_g + col0 + ct*32, rc[ct]);
    }
  }

  // ---- phase F: new_slots = mu[a] + sigma[a]*z ----
  {
    const int frow = t >> 4;
    const int fdp  = (t & 15) * 4;
    const int fa   = am_l[frow];
    float4 fz = *(const float4*)(z  + (size_t)(R0 + frow)*DD + fdp);
    float4 fm = *(const float4*)(mu + (size_t)fa*DD + fdp);
    float4 fs = *(const float4*)(ws + SIG_OFF + (size_t)fa*DD + fdp);
    float4 o;
    o.x = fmaf(fs.x, fz.x, fm.x); o.y = fmaf(fs.y, fz.y, fm.y);
    o.z = fmaf(fs.z, fz.z, fm.z); o.w = fmaf(fs.w, fz.w, fm.w);
    *(float4*)(out_slots + (size_t)(R0 + frow)*DD + fdp) = o;
  }
}

__device__ __forceinline__ float block_max_1024(float v, float* red) {
  #pragma unroll
  for (int off = 32; off; off >>= 1) v = fmaxf(v, __shfl_xor(v, off));
  int wave = threadIdx.x >> 6, lane = threadIdx.x & 63;
  if (lane == 0) red[wave] = v;
  __syncthreads();
  float m = red[0];
  #pragma unroll
  for (int w = 1; w < 16; ++w) m = fmaxf(m, red[w]);
  __syncthreads();
  return m;
}

__device__ __forceinline__ float block_sum_1024(float v, float* red) {
  #pragma unroll
  for (int off = 32; off; off >>= 1) v += __shfl_xor(v, off);
  int wave = threadIdx.x >> 6, lane = threadIdx.x & 63;
  if (lane == 0) red[wave] = v;
  __syncthreads();
  float s = 0.0f;
  #pragma unroll
  for (int w = 0; w < 16; ++w) s += red[w];
  __syncthreads();
  return s;
}

__global__ __launch_bounds__(1024) void finalize_kernel(
    const float* __restrict__ log_prior, const float* __restrict__ resp_g,
    float* __restrict__ out_prior) {
  __shared__ float red[16];
  int t = threadIdx.x;
  float lp = log_prior[t];
  float rs = resp_g[t];

  float m1 = block_max_1024(lp, red);
  float e1 = __expf(lp - m1);
  float s1 = block_sum_1024(e1, red);

  float m2 = block_max_1024(rs, red);
  float e2 = __expf(rs - m2);
  float s2 = block_sum_1024(e2, red);

  out_prior[t] = DECAY * (e1 / s1) + (1.0f - DECAY) * (e2 / s2);
}

extern "C" void kernel_launch(void* const* d_in, const int* in_sizes, int n_in,
                              void* d_out, int out_size, void* d_ws, size_t ws_size,
                              hipStream_t stream) {
  const float* slots     = (const float*)d_in[0];
  const float* mu        = (const float*)d_in[1];
  const float* log_sigma = (const float*)d_in[2];
  const float* log_prior = (const float*)d_in[3];
  const float* z         = (const float*)d_in[4];

  float* out       = (float*)d_out;
  float* out_slots = out;                       // [BS*DD]
  float* out_ll    = out + (size_t)BS*DD;       // [BS]
  float* out_prior = out + (size_t)BS*DD + BS;  // [KK]
  float* ws        = (float*)d_ws;

  (void)hipFuncSetAttribute((const void*)main_kernel,
                            hipFuncAttributeMaxDynamicSharedMemorySize,
                            SMEM_BYTES);

  hipMemsetAsync(ws + RESP_OFF, 0, KK*sizeof(float), stream);
  prep_kernel<<<KK, 64, 0, stream>>>(mu, log_sigma, ws);
  main_kernel<<<NBLK, NTHR, SMEM_BYTES, stream>>>(slots, mu, z, ws, out_slots,
                                                  out_ll, ws + RESP_OFF);
  finalize_kernel<<<1, 1024, 0, stream>>>(log_prior, ws + RESP_OFF, out_prior);
}